// Round 1
// baseline (645.697 us; speedup 1.0000x reference)
//
#include <hip/hip_runtime.h>
#include <hip/hip_bf16.h>

// Problem constants (match reference)
#define NN 20000
#define EE 640000
#define DD 256
#define GG 64
#define ETOT (EE + NN)   // edges + self loops = 660000
#define BN_EPS 1e-5f
#define CAP 1024         // per-chunk edge capacity in LDS for aggregation

// ---------------------------------------------------------------------------
// CSR build: histogram -> scan -> scatter (grouped by destination node)
// ---------------------------------------------------------------------------
__global__ void hist_kernel(const int* __restrict__ ei, int* __restrict__ counts) {
    int i = blockIdx.x * blockDim.x + threadIdx.x;
    int stride = gridDim.x * blockDim.x;
    for (; i < ETOT; i += stride) {
        int dst = (i < EE) ? ei[EE + i] : (i - EE);
        atomicAdd(&counts[dst], 1);
    }
}

__global__ __launch_bounds__(1024) void scan_kernel(const int* __restrict__ counts,
                                                    int* __restrict__ offsets,
                                                    int* __restrict__ cursor) {
    __shared__ int sd[1024];
    __shared__ int carry_s;
    int tid = threadIdx.x;
    if (tid == 0) carry_s = 0;
    __syncthreads();
    for (int base = 0; base < NN; base += 1024) {
        int i = base + tid;
        int v = (i < NN) ? counts[i] : 0;
        sd[tid] = v;
        __syncthreads();
        for (int o = 1; o < 1024; o <<= 1) {
            int t = (tid >= o) ? sd[tid - o] : 0;
            __syncthreads();
            sd[tid] += t;
            __syncthreads();
        }
        int carry = carry_s;   // stable: last write was before prior barrier
        if (i < NN) {
            int ex = carry + sd[tid] - v;   // exclusive
            offsets[i] = ex;
            cursor[i] = ex;
        }
        __syncthreads();
        if (tid == 1023) carry_s = carry + sd[1023];
        __syncthreads();
    }
    if (tid == 0) offsets[NN] = carry_s;
}

__global__ void scatter_kernel(const int* __restrict__ ei, int* __restrict__ cursor,
                               int* __restrict__ csr_src) {
    int i = blockIdx.x * blockDim.x + threadIdx.x;
    int stride = gridDim.x * blockDim.x;
    for (; i < ETOT; i += stride) {
        int s, d;
        if (i < EE) { s = ei[i]; d = ei[EE + i]; }
        else        { s = i - EE; d = i - EE; }
        int pos = atomicAdd(&cursor[d], 1);
        csr_src[pos] = s;
    }
}

// ---------------------------------------------------------------------------
// fp32 tiled GEMM: C[M x 256] = A[M x 256] @ B[256 x 256]   (row-major)
// ---------------------------------------------------------------------------
#define BM 64
#define BN 64
#define BK 16
__global__ __launch_bounds__(256) void gemm_kernel(const float* __restrict__ A,
                                                   const float* __restrict__ B,
                                                   float* __restrict__ C, int M) {
    __shared__ float As[BM][BK + 1];
    __shared__ float Bs[BK][BN + 1];
    int tid = threadIdx.x;
    int row0 = blockIdx.y * BM;
    int col0 = blockIdx.x * BN;
    int ty = tid >> 4, tx = tid & 15;
    float c[4][4] = {};
    for (int k0 = 0; k0 < DD; k0 += BK) {
        #pragma unroll
        for (int i = 0; i < 4; ++i) {
            int idx = i * 256 + tid;
            int r = idx >> 4, k = idx & 15;
            int gr = row0 + r;
            As[r][k] = (gr < M) ? A[gr * DD + k0 + k] : 0.f;
        }
        #pragma unroll
        for (int i = 0; i < 4; ++i) {
            int idx = i * 256 + tid;
            int k = idx >> 6, cc = idx & 63;
            Bs[k][cc] = B[(k0 + k) * DD + col0 + cc];
        }
        __syncthreads();
        #pragma unroll
        for (int k = 0; k < BK; ++k) {
            float a[4], b[4];
            #pragma unroll
            for (int i = 0; i < 4; ++i) a[i] = As[ty * 4 + i][k];
            #pragma unroll
            for (int j = 0; j < 4; ++j) b[j] = Bs[k][tx * 4 + j];
            #pragma unroll
            for (int i = 0; i < 4; ++i)
                #pragma unroll
                for (int j = 0; j < 4; ++j)
                    c[i][j] += a[i] * b[j];
        }
        __syncthreads();
    }
    #pragma unroll
    for (int i = 0; i < 4; ++i) {
        int gr = row0 + ty * 4 + i;
        if (gr < M) {
            #pragma unroll
            for (int j = 0; j < 4; ++j)
                C[gr * DD + col0 + tx * 4 + j] = c[i][j];
        }
    }
}

// ---------------------------------------------------------------------------
// per-node matvec: as_[n] = h[n,:].a_src ; ad_[n] = h[n,:].a_dst
// ---------------------------------------------------------------------------
__global__ __launch_bounds__(256) void matvec_kernel(const float* __restrict__ h,
                                                     const float* __restrict__ a_src,
                                                     const float* __restrict__ a_dst,
                                                     float* __restrict__ as_,
                                                     float* __restrict__ ad_) {
    __shared__ float sbuf[8];
    int node = blockIdx.x;
    int f = threadIdx.x;
    float v = h[node * DD + f];
    float p1 = v * a_src[f];
    float p2 = v * a_dst[f];
    #pragma unroll
    for (int o = 32; o > 0; o >>= 1) {
        p1 += __shfl_down(p1, o, 64);
        p2 += __shfl_down(p2, o, 64);
    }
    int wid = f >> 6;
    if ((f & 63) == 0) { sbuf[wid] = p1; sbuf[4 + wid] = p2; }
    __syncthreads();
    if (f == 0) {
        float r1 = 0.f, r2 = 0.f;
        #pragma unroll
        for (int w = 0; w < 4; ++w) { r1 += sbuf[w]; r2 += sbuf[4 + w]; }
        as_[node] = r1;
        ad_[node] = r2;
    }
}

// ---------------------------------------------------------------------------
// Per-dst-node gather aggregation with online softmax.
// block = 256 threads, one block per destination node; thread t owns feature t.
// out[n][f] = lrelu_0.01( (sum_j alpha_j * h[src_j][f]) + bias[f] )
// ---------------------------------------------------------------------------
__device__ __forceinline__ float block_reduce(float v, float* sbuf, bool is_max) {
    #pragma unroll
    for (int o = 32; o > 0; o >>= 1) {
        float t = __shfl_down(v, o, 64);
        v = is_max ? fmaxf(v, t) : v + t;
    }
    int tid = threadIdx.x;
    int wid = tid >> 6;
    if ((tid & 63) == 0) sbuf[wid] = v;
    __syncthreads();
    if (tid == 0) {
        float r = sbuf[0];
        #pragma unroll
        for (int w = 1; w < 4; ++w) r = is_max ? fmaxf(r, sbuf[w]) : r + sbuf[w];
        sbuf[0] = r;
    }
    __syncthreads();
    float r = sbuf[0];
    __syncthreads();
    return r;
}

__global__ __launch_bounds__(256) void aggregate_kernel(const float* __restrict__ h,
                                                        const int* __restrict__ csr_src,
                                                        const int* __restrict__ offsets,
                                                        const float* __restrict__ as_,
                                                        const float* __restrict__ ad_,
                                                        const float* __restrict__ bias,
                                                        float* __restrict__ out) {
    __shared__ float e_sh[CAP];
    __shared__ int   src_sh[CAP];
    __shared__ float sbuf[4];
    int n = blockIdx.x;
    int f = threadIdx.x;
    int off = offsets[n];
    int deg = offsets[n + 1] - off;
    float adn = ad_[n];

    float m = -INFINITY, s = 0.f, acc = 0.f;
    for (int cs = 0; cs < deg; cs += CAP) {
        int cl = min(CAP, deg - cs);
        // phase 1: compute e = lrelu_0.2(as[src] + ad[n]) into LDS, find chunk max
        float lmax = -INFINITY;
        for (int j = f; j < cl; j += 256) {
            int sidx = csr_src[off + cs + j];
            float e = as_[sidx] + adn;
            e = (e > 0.f) ? e : 0.2f * e;
            src_sh[j] = sidx;
            e_sh[j] = e;
            lmax = fmaxf(lmax, e);
        }
        float cm = block_reduce(lmax, sbuf, true);
        float newm = fmaxf(m, cm);
        float scale = expf(m - newm);   // exp(-inf) == 0 on first chunk
        // phase 2: exponentiate, chunk sum
        float lsum = 0.f;
        for (int j = f; j < cl; j += 256) {
            float ex = expf(e_sh[j] - newm);
            e_sh[j] = ex;
            lsum += ex;
        }
        float csum = block_reduce(lsum, sbuf, false);
        s = s * scale + csum;
        // phase 3: accumulate features
        acc *= scale;
        int j = 0;
        for (; j + 4 <= cl; j += 4) {
            float e0 = e_sh[j], e1 = e_sh[j + 1], e2 = e_sh[j + 2], e3 = e_sh[j + 3];
            int s0 = src_sh[j], s1 = src_sh[j + 1], s2 = src_sh[j + 2], s3 = src_sh[j + 3];
            acc += e0 * h[s0 * DD + f];
            acc += e1 * h[s1 * DD + f];
            acc += e2 * h[s2 * DD + f];
            acc += e3 * h[s3 * DD + f];
        }
        for (; j < cl; ++j)
            acc += e_sh[j] * h[src_sh[j] * DD + f];
        m = newm;
        __syncthreads();   // protect LDS before next chunk
    }
    float r = acc / s + bias[f];
    out[n * DD + f] = (r > 0.f) ? r : 0.01f * r;
}

// ---------------------------------------------------------------------------
// BatchNorm (eval) + pooled sums via atomics; counts; final linear
// ---------------------------------------------------------------------------
__global__ void bnpool_kernel(const float* __restrict__ h, const int* __restrict__ batch,
                              const float* __restrict__ gam, const float* __restrict__ bet,
                              const float* __restrict__ mean, const float* __restrict__ var,
                              float* __restrict__ pool) {
    int i = blockIdx.x * blockDim.x + threadIdx.x;
    int stride = gridDim.x * blockDim.x;
    for (; i < NN * DD; i += stride) {
        int node = i >> 8, f = i & 255;
        float v = (h[i] - mean[f]) * rsqrtf(var[f] + BN_EPS) * gam[f] + bet[f];
        atomicAdd(&pool[batch[node] * DD + f], v);
    }
}

__global__ void cnt_kernel(const int* __restrict__ batch, float* __restrict__ cnt) {
    int i = blockIdx.x * blockDim.x + threadIdx.x;
    if (i < NN) atomicAdd(&cnt[batch[i]], 1.f);
}

__global__ __launch_bounds__(256) void final_kernel(const float* __restrict__ pool,
                                                    const float* __restrict__ cnt,
                                                    const float* __restrict__ Wl,
                                                    const float* __restrict__ bl,
                                                    float* __restrict__ out) {
    __shared__ float p_sh[DD];
    int g = blockIdx.x, j = threadIdx.x;
    float c = fmaxf(cnt[g], 1.f);
    p_sh[j] = pool[g * DD + j] / c;
    __syncthreads();
    float acc = 0.f;
    for (int fi = 0; fi < DD; ++fi)
        acc += p_sh[fi] * Wl[j * DD + fi];
    out[g * DD + j] = acc + bl[j];
}

// ---------------------------------------------------------------------------
extern "C" void kernel_launch(void* const* d_in, const int* in_sizes, int n_in,
                              void* d_out, int out_size, void* d_ws, size_t ws_size,
                              hipStream_t stream) {
    const float* x       = (const float*)d_in[0];
    const int*   ei      = (const int*)d_in[1];
    const int*   batch   = (const int*)d_in[2];
    const float* W1      = (const float*)d_in[3];
    const float* a1_src  = (const float*)d_in[4];
    const float* a1_dst  = (const float*)d_in[5];
    const float* b1      = (const float*)d_in[6];
    const float* W2      = (const float*)d_in[7];
    const float* a2_src  = (const float*)d_in[8];
    const float* a2_dst  = (const float*)d_in[9];
    const float* b2      = (const float*)d_in[10];
    const float* bn_g    = (const float*)d_in[11];
    const float* bn_b    = (const float*)d_in[12];
    const float* bn_m    = (const float*)d_in[13];
    const float* bn_v    = (const float*)d_in[14];
    const float* Wl      = (const float*)d_in[15];
    const float* bl      = (const float*)d_in[16];
    float* out = (float*)d_out;

    // workspace layout (256B aligned slabs)
    char* ws = (char*)d_ws;
    size_t o = 0;
    auto take = [&](size_t bytes) { char* p = ws + o; o += (bytes + 255) & ~(size_t)255; return p; };
    int*   counts  = (int*)  take(NN * 4);
    int*   offsets = (int*)  take((NN + 1) * 4);
    int*   cursor  = (int*)  take(NN * 4);
    int*   csr_src = (int*)  take((size_t)ETOT * 4);
    float* as_     = (float*)take(NN * 4);
    float* ad_     = (float*)take(NN * 4);
    float* bufA    = (float*)take((size_t)NN * DD * 4);
    float* bufB    = (float*)take((size_t)NN * DD * 4);
    float* pool    = (float*)take(GG * DD * 4);
    float* cnt     = (float*)take(GG * 4);
    (void)ws_size; (void)in_sizes; (void)n_in; (void)out_size;

    // zero what needs zeroing (every call: harness does not re-poison)
    hipMemsetAsync(counts, 0, NN * 4, stream);
    hipMemsetAsync(pool, 0, GG * DD * 4, stream);
    hipMemsetAsync(cnt, 0, GG * 4, stream);

    // CSR build (edge_index is constant across both layers)
    hist_kernel<<<2579, 256, 0, stream>>>(ei, counts);
    scan_kernel<<<1, 1024, 0, stream>>>(counts, offsets, cursor);
    scatter_kernel<<<2579, 256, 0, stream>>>(ei, cursor, csr_src);

    dim3 ggrid(DD / BN, (NN + BM - 1) / BM);

    // ---- layer 1 ----
    gemm_kernel<<<ggrid, 256, 0, stream>>>(x, W1, bufA, NN);
    matvec_kernel<<<NN, 256, 0, stream>>>(bufA, a1_src, a1_dst, as_, ad_);
    aggregate_kernel<<<NN, 256, 0, stream>>>(bufA, csr_src, offsets, as_, ad_, b1, bufB);

    // ---- layer 2 ----
    gemm_kernel<<<ggrid, 256, 0, stream>>>(bufB, W2, bufA, NN);
    matvec_kernel<<<NN, 256, 0, stream>>>(bufA, a2_src, a2_dst, as_, ad_);
    aggregate_kernel<<<NN, 256, 0, stream>>>(bufA, csr_src, offsets, as_, ad_, b2, bufB);

    // ---- BN + pool + linear ----
    bnpool_kernel<<<4096, 256, 0, stream>>>(bufB, batch, bn_g, bn_b, bn_m, bn_v, pool);
    cnt_kernel<<<(NN + 255) / 256, 256, 0, stream>>>(batch, cnt);
    final_kernel<<<GG, 256, 0, stream>>>(pool, cnt, Wl, bl, out);
}

// Round 2
// 374.280 us; speedup vs baseline: 1.7252x; 1.7252x over previous
//
#include <hip/hip_runtime.h>
#include <hip/hip_bf16.h>

// Problem constants (match reference)
#define NN 20000
#define EE 640000
#define DD 256
#define GG 64
#define ETOT (EE + NN)   // edges + self loops = 660000
#define BN_EPS 1e-5f
#define CAP 128          // per-chunk edge capacity in LDS (max degree ~70)

typedef short s16x8 __attribute__((ext_vector_type(8)));
typedef float f32x4 __attribute__((ext_vector_type(4)));

__device__ __forceinline__ unsigned short f2bf_hi(float x) {
    unsigned u = __float_as_uint(x);
    unsigned r = (u + 0x7FFFu + ((u >> 16) & 1u)) >> 16;   // RNE
    return (unsigned short)r;
}
__device__ __forceinline__ float bf2f(unsigned short h) {
    return __uint_as_float(((unsigned)h) << 16);
}

// ---------------------------------------------------------------------------
// Graph-boundary prep: batch is SORTED -> binary search, no atomics.
// start[g] = first node with batch >= g ; cntf[g] = nodes in graph g
// ---------------------------------------------------------------------------
__global__ void prep_kernel(const int* __restrict__ batch, int* __restrict__ start,
                            float* __restrict__ cntf) {
    int g = threadIdx.x;
    if (g <= GG) {
        if (g == GG) start[GG] = NN;
        else {
            int lo = 0, hi = NN;
            while (lo < hi) { int mid = (lo + hi) >> 1; if (batch[mid] < g) lo = mid + 1; else hi = mid; }
            start[g] = lo;
        }
    }
    __syncthreads();
    if (g < GG) cntf[g] = (float)(start[g + 1] - start[g]);
}

// ---------------------------------------------------------------------------
// CSR build: histogram -> scan -> scatter (grouped by destination node)
// ---------------------------------------------------------------------------
__global__ void hist_kernel(const int* __restrict__ ei, int* __restrict__ counts) {
    int i = blockIdx.x * blockDim.x + threadIdx.x;
    int stride = gridDim.x * blockDim.x;
    for (; i < ETOT; i += stride) {
        int dst = (i < EE) ? ei[EE + i] : (i - EE);
        atomicAdd(&counts[dst], 1);
    }
}

__global__ __launch_bounds__(1024) void scan_kernel(const int* __restrict__ counts,
                                                    int* __restrict__ offsets,
                                                    int* __restrict__ cursor) {
    __shared__ int wsum[16];
    __shared__ int carry_s;
    int tid = threadIdx.x, lane = tid & 63, wid = tid >> 6;
    if (tid == 0) carry_s = 0;
    __syncthreads();
    for (int base = 0; base < NN; base += 1024) {
        int i = base + tid;
        int v = (i < NN) ? counts[i] : 0;
        int x = v;
        #pragma unroll
        for (int o = 1; o < 64; o <<= 1) { int t = __shfl_up(x, o, 64); if (lane >= o) x += t; }
        if (lane == 63) wsum[wid] = x;
        __syncthreads();
        if (wid == 0) {
            int wv = (lane < 16) ? wsum[lane] : 0;
            #pragma unroll
            for (int o = 1; o < 16; o <<= 1) { int t = __shfl_up(wv, o, 64); if (lane >= o) wv += t; }
            if (lane < 16) wsum[lane] = wv;   // inclusive over wave sums
        }
        __syncthreads();
        int wbase = wid ? wsum[wid - 1] : 0;
        int carry = carry_s;
        if (i < NN) {
            int ex = carry + wbase + x - v;   // exclusive
            offsets[i] = ex;
            cursor[i] = ex;
        }
        __syncthreads();                      // all reads of carry_s/wsum done
        if (tid == 0) carry_s = carry + wsum[15];
        __syncthreads();                      // carry update visible, wsum free
    }
    if (threadIdx.x == 0) offsets[NN] = carry_s;
}

__global__ void scatter_kernel(const int* __restrict__ ei, int* __restrict__ cursor,
                               int* __restrict__ csr_src) {
    int i = blockIdx.x * blockDim.x + threadIdx.x;
    int stride = gridDim.x * blockDim.x;
    for (; i < ETOT; i += stride) {
        int s, d;
        if (i < EE) { s = ei[i]; d = ei[EE + i]; }
        else        { s = i - EE; d = i - EE; }
        int pos = atomicAdd(&cursor[d], 1);
        csr_src[pos] = s;
    }
}

// ---------------------------------------------------------------------------
// Weight conversion: W[k][n] fp32 -> BhT/BlT [n][k] bf16 (hi + residual-lo)
// ---------------------------------------------------------------------------
__global__ __launch_bounds__(256) void convB_kernel(const float* __restrict__ B,
                                                    short* __restrict__ BhT,
                                                    short* __restrict__ BlT) {
    int n = blockIdx.x, k = threadIdx.x;
    float x = B[k * DD + n];
    unsigned short hb = f2bf_hi(x);
    BhT[n * DD + k] = (short)hb;
    BlT[n * DD + k] = (short)f2bf_hi(x - bf2f(hb));
}

// ---------------------------------------------------------------------------
// MFMA GEMM: C[M x 256] = A[M x 256] @ W[256 x 256]
// split-bf16 3-pass (AhBh + AhBl + AlBh) for ~fp32 accuracy.
// 128x128 tile, BK=64, 4 waves (2x2), 16x16x32 bf16 MFMA, XOR-swizzled LDS.
// ---------------------------------------------------------------------------
#define GBM 128
#define GBN 128
#define GBK 64

__global__ __launch_bounds__(256) void gemm_mfma_kernel(const float* __restrict__ A,
                                                        const short* __restrict__ BhT,
                                                        const short* __restrict__ BlT,
                                                        float* __restrict__ C, int M) {
    __shared__ short As_h[GBM * GBK];
    __shared__ short As_l[GBM * GBK];
    __shared__ short Bs_h[GBN * GBK];
    __shared__ short Bs_l[GBN * GBK];
    int tid = threadIdx.x;
    int row0 = blockIdx.y * GBM;
    int col0 = blockIdx.x * GBN;
    int w = tid >> 6, lane = tid & 63;
    int wr = w >> 1, wc = w & 1;

    f32x4 acc[4][4];
    #pragma unroll
    for (int m = 0; m < 4; ++m)
        #pragma unroll
        for (int n = 0; n < 4; ++n)
            acc[m][n] = (f32x4){0.f, 0.f, 0.f, 0.f};

    int srow = tid >> 3;     // 0..31
    int sslot = tid & 7;     // 0..7  (16B slot within a 128B row)

    for (int k0 = 0; k0 < DD; k0 += GBK) {
        __syncthreads();     // previous iter's LDS reads complete
        #pragma unroll
        for (int p = 0; p < 4; ++p) {
            int r = p * 32 + srow;
            int gr = row0 + r;
            float xv[8];
            if (gr < M) {
                const float4* ap = (const float4*)(A + (size_t)gr * DD + k0 + sslot * 8);
                float4 a0 = ap[0], a1 = ap[1];
                xv[0] = a0.x; xv[1] = a0.y; xv[2] = a0.z; xv[3] = a0.w;
                xv[4] = a1.x; xv[5] = a1.y; xv[6] = a1.z; xv[7] = a1.w;
            } else {
                #pragma unroll
                for (int i = 0; i < 8; ++i) xv[i] = 0.f;
            }
            s16x8 hv, lv;
            #pragma unroll
            for (int i = 0; i < 8; ++i) {
                unsigned short hb = f2bf_hi(xv[i]);
                hv[i] = (short)hb;
                lv[i] = (short)f2bf_hi(xv[i] - bf2f(hb));
            }
            int byte = r * 128 + ((sslot ^ (r & 7)) << 4);
            *(s16x8*)((char*)As_h + byte) = hv;
            *(s16x8*)((char*)As_l + byte) = lv;
            // B tiles: pre-converted bf16, [n][k] layout -> coalesced 16B loads
            const short* bhp = BhT + (size_t)(col0 + r) * DD + k0 + sslot * 8;
            const short* blp = BlT + (size_t)(col0 + r) * DD + k0 + sslot * 8;
            *(s16x8*)((char*)Bs_h + byte) = *(const s16x8*)bhp;
            *(s16x8*)((char*)Bs_l + byte) = *(const s16x8*)blp;
        }
        __syncthreads();

        #pragma unroll
        for (int ks = 0; ks < 2; ++ks) {
            s16x8 ah[4], al[4], bh[4], bl[4];
            int g = ks * 4 + (lane >> 4);
            #pragma unroll
            for (int m = 0; m < 4; ++m) {
                int r = wr * 64 + m * 16 + (lane & 15);
                int byte = r * 128 + ((g ^ (r & 7)) << 4);
                ah[m] = *(const s16x8*)((char*)As_h + byte);
                al[m] = *(const s16x8*)((char*)As_l + byte);
            }
            #pragma unroll
            for (int n = 0; n < 4; ++n) {
                int c = wc * 64 + n * 16 + (lane & 15);
                int byte = c * 128 + ((g ^ (c & 7)) << 4);
                bh[n] = *(const s16x8*)((char*)Bs_h + byte);
                bl[n] = *(const s16x8*)((char*)Bs_l + byte);
            }
            #pragma unroll
            for (int m = 0; m < 4; ++m)
                #pragma unroll
                for (int n = 0; n < 4; ++n) {
                    acc[m][n] = __builtin_amdgcn_mfma_f32_16x16x32_bf16(ah[m], bh[n], acc[m][n], 0, 0, 0);
                    acc[m][n] = __builtin_amdgcn_mfma_f32_16x16x32_bf16(ah[m], bl[n], acc[m][n], 0, 0, 0);
                    acc[m][n] = __builtin_amdgcn_mfma_f32_16x16x32_bf16(al[m], bh[n], acc[m][n], 0, 0, 0);
                }
        }
    }

    // epilogue: C/D layout col=lane&15, row=(lane>>4)*4+reg (m89-verified)
    #pragma unroll
    for (int m = 0; m < 4; ++m) {
        int rbase = row0 + wr * 64 + m * 16 + ((lane >> 4) << 2);
        #pragma unroll
        for (int n = 0; n < 4; ++n) {
            int cg = col0 + wc * 64 + n * 16 + (lane & 15);
            #pragma unroll
            for (int j = 0; j < 4; ++j) {
                int rg = rbase + j;
                if (rg < M) C[(size_t)rg * DD + cg] = acc[m][n][j];
            }
        }
    }
}

// ---------------------------------------------------------------------------
// per-node matvec: as_[n] = h[n,:].a_src ; ad_[n] = h[n,:].a_dst
// ---------------------------------------------------------------------------
__global__ __launch_bounds__(256) void matvec_kernel(const float* __restrict__ h,
                                                     const float* __restrict__ a_src,
                                                     const float* __restrict__ a_dst,
                                                     float* __restrict__ as_,
                                                     float* __restrict__ ad_) {
    __shared__ float sbuf[8];
    int node = blockIdx.x;
    int f = threadIdx.x;
    float v = h[node * DD + f];
    float p1 = v * a_src[f];
    float p2 = v * a_dst[f];
    #pragma unroll
    for (int o = 32; o > 0; o >>= 1) {
        p1 += __shfl_down(p1, o, 64);
        p2 += __shfl_down(p2, o, 64);
    }
    int wid = f >> 6;
    if ((f & 63) == 0) { sbuf[wid] = p1; sbuf[4 + wid] = p2; }
    __syncthreads();
    if (f == 0) {
        float r1 = 0.f, r2 = 0.f;
        #pragma unroll
        for (int wq = 0; wq < 4; ++wq) { r1 += sbuf[wq]; r2 += sbuf[4 + wq]; }
        as_[node] = r1;
        ad_[node] = r2;
    }
}

// ---------------------------------------------------------------------------
// Per-dst-node gather aggregation with online softmax (block per node)
// ---------------------------------------------------------------------------
__device__ __forceinline__ float block_reduce(float v, float* sbuf, bool is_max) {
    #pragma unroll
    for (int o = 32; o > 0; o >>= 1) {
        float t = __shfl_down(v, o, 64);
        v = is_max ? fmaxf(v, t) : v + t;
    }
    int tid = threadIdx.x;
    int wid = tid >> 6;
    if ((tid & 63) == 0) sbuf[wid] = v;
    __syncthreads();
    if (tid == 0) {
        float r = sbuf[0];
        #pragma unroll
        for (int wq = 1; wq < 4; ++wq) r = is_max ? fmaxf(r, sbuf[wq]) : r + sbuf[wq];
        sbuf[0] = r;
    }
    __syncthreads();
    float r = sbuf[0];
    __syncthreads();
    return r;
}

__global__ __launch_bounds__(256) void aggregate_kernel(const float* __restrict__ h,
                                                        const int* __restrict__ csr_src,
                                                        const int* __restrict__ offsets,
                                                        const float* __restrict__ as_,
                                                        const float* __restrict__ ad_,
                                                        const float* __restrict__ bias,
                                                        float* __restrict__ out) {
    __shared__ float e_sh[CAP];
    __shared__ int   src_sh[CAP];
    __shared__ float sbuf[4];
    int n = blockIdx.x;
    int f = threadIdx.x;
    int off = offsets[n];
    int deg = offsets[n + 1] - off;
    float adn = ad_[n];

    float m = -INFINITY, s = 0.f, acc = 0.f;
    for (int cs = 0; cs < deg; cs += CAP) {
        int cl = min(CAP, deg - cs);
        float lmax = -INFINITY;
        for (int j = f; j < cl; j += 256) {
            int sidx = csr_src[off + cs + j];
            float e = as_[sidx] + adn;
            e = (e > 0.f) ? e : 0.2f * e;
            src_sh[j] = sidx;
            e_sh[j] = e;
            lmax = fmaxf(lmax, e);
        }
        float cm = block_reduce(lmax, sbuf, true);
        float newm = fmaxf(m, cm);
        float scale = expf(m - newm);   // exp(-inf)==0 on first chunk
        float lsum = 0.f;
        for (int j = f; j < cl; j += 256) {
            float ex = expf(e_sh[j] - newm);
            e_sh[j] = ex;
            lsum += ex;
        }
        float csum = block_reduce(lsum, sbuf, false);
        s = s * scale + csum;
        acc *= scale;
        int j = 0;
        for (; j + 4 <= cl; j += 4) {
            float e0 = e_sh[j], e1 = e_sh[j + 1], e2 = e_sh[j + 2], e3 = e_sh[j + 3];
            int s0 = src_sh[j], s1 = src_sh[j + 1], s2 = src_sh[j + 2], s3 = src_sh[j + 3];
            acc += e0 * h[s0 * DD + f];
            acc += e1 * h[s1 * DD + f];
            acc += e2 * h[s2 * DD + f];
            acc += e3 * h[s3 * DD + f];
        }
        for (; j < cl; ++j)
            acc += e_sh[j] * h[src_sh[j] * DD + f];
        m = newm;
        __syncthreads();
    }
    float r = acc / s + bias[f];
    out[n * DD + f] = (r > 0.f) ? r : 0.01f * r;
}

// ---------------------------------------------------------------------------
// Pool: plain segment sums over sorted node ranges (BN folded into final)
// ---------------------------------------------------------------------------
#define PSLICE 8
__global__ __launch_bounds__(256) void pool_kernel(const float* __restrict__ h,
                                                   const int* __restrict__ start,
                                                   float* __restrict__ pool) {
    int g = blockIdx.x >> 3, sl = blockIdx.x & (PSLICE - 1);
    int f = threadIdx.x;
    int s0 = start[g], s1 = start[g + 1];
    float acc = 0.f;
    for (int nd = s0 + sl; nd < s1; nd += PSLICE)
        acc += h[(size_t)nd * DD + f];
    if (acc != 0.f || sl == 0) atomicAdd(&pool[g * DD + f], acc);
}

__global__ __launch_bounds__(256) void final_kernel(const float* __restrict__ pool,
                                                    const float* __restrict__ cnt,
                                                    const float* __restrict__ gam,
                                                    const float* __restrict__ bet,
                                                    const float* __restrict__ mean,
                                                    const float* __restrict__ var,
                                                    const float* __restrict__ Wl,
                                                    const float* __restrict__ bl,
                                                    float* __restrict__ out) {
    __shared__ float p_sh[DD];
    int g = blockIdx.x, j = threadIdx.x;
    float cn = cnt[g];
    float scale = gam[j] * rsqrtf(var[j] + BN_EPS);
    p_sh[j] = (cn > 0.f) ? (pool[g * DD + j] / cn - mean[j]) * scale + bet[j] : 0.f;
    __syncthreads();
    float acc = 0.f;
    for (int fi = 0; fi < DD; ++fi)
        acc += p_sh[fi] * Wl[j * DD + fi];
    out[g * DD + j] = acc + bl[j];
}

// ---------------------------------------------------------------------------
extern "C" void kernel_launch(void* const* d_in, const int* in_sizes, int n_in,
                              void* d_out, int out_size, void* d_ws, size_t ws_size,
                              hipStream_t stream) {
    const float* x       = (const float*)d_in[0];
    const int*   ei      = (const int*)d_in[1];
    const int*   batch   = (const int*)d_in[2];
    const float* W1      = (const float*)d_in[3];
    const float* a1_src  = (const float*)d_in[4];
    const float* a1_dst  = (const float*)d_in[5];
    const float* b1      = (const float*)d_in[6];
    const float* W2      = (const float*)d_in[7];
    const float* a2_src  = (const float*)d_in[8];
    const float* a2_dst  = (const float*)d_in[9];
    const float* b2      = (const float*)d_in[10];
    const float* bn_g    = (const float*)d_in[11];
    const float* bn_b    = (const float*)d_in[12];
    const float* bn_m    = (const float*)d_in[13];
    const float* bn_v    = (const float*)d_in[14];
    const float* Wl      = (const float*)d_in[15];
    const float* bl      = (const float*)d_in[16];
    float* out = (float*)d_out;

    char* ws = (char*)d_ws;
    size_t o = 0;
    auto take = [&](size_t bytes) { char* p = ws + o; o += (bytes + 255) & ~(size_t)255; return p; };
    int*   counts  = (int*)  take(NN * 4);
    int*   offsets = (int*)  take((NN + 1) * 4);
    int*   cursor  = (int*)  take(NN * 4);
    int*   csr_src = (int*)  take((size_t)ETOT * 4);
    float* as_     = (float*)take(NN * 4);
    float* ad_     = (float*)take(NN * 4);
    float* bufA    = (float*)take((size_t)NN * DD * 4);
    float* bufB    = (float*)take((size_t)NN * DD * 4);
    float* pool    = (float*)take(GG * DD * 4);
    float* cnt     = (float*)take(GG * 4);
    int*   start   = (int*)  take((GG + 1) * 4);
    short* BhT1    = (short*)take((size_t)DD * DD * 2);
    short* BlT1    = (short*)take((size_t)DD * DD * 2);
    short* BhT2    = (short*)take((size_t)DD * DD * 2);
    short* BlT2    = (short*)take((size_t)DD * DD * 2);
    (void)ws_size; (void)in_sizes; (void)n_in; (void)out_size;

    hipMemsetAsync(counts, 0, NN * 4, stream);
    hipMemsetAsync(pool, 0, GG * DD * 4, stream);

    // prep + CSR build
    prep_kernel<<<1, 128, 0, stream>>>(batch, start, cnt);
    hist_kernel<<<2579, 256, 0, stream>>>(ei, counts);
    scan_kernel<<<1, 1024, 0, stream>>>(counts, offsets, cursor);
    scatter_kernel<<<2579, 256, 0, stream>>>(ei, cursor, csr_src);

    // weight conversions (hi/lo bf16, transposed)
    convB_kernel<<<DD, 256, 0, stream>>>(W1, BhT1, BlT1);
    convB_kernel<<<DD, 256, 0, stream>>>(W2, BhT2, BlT2);

    dim3 ggrid(DD / GBN, (NN + GBM - 1) / GBM);

    // ---- layer 1 ----
    gemm_mfma_kernel<<<ggrid, 256, 0, stream>>>(x, BhT1, BlT1, bufA, NN);
    matvec_kernel<<<NN, 256, 0, stream>>>(bufA, a1_src, a1_dst, as_, ad_);
    aggregate_kernel<<<NN, 256, 0, stream>>>(bufA, csr_src, offsets, as_, ad_, b1, bufB);

    // ---- layer 2 ----
    gemm_mfma_kernel<<<ggrid, 256, 0, stream>>>(bufB, BhT2, BlT2, bufA, NN);
    matvec_kernel<<<NN, 256, 0, stream>>>(bufA, a2_src, a2_dst, as_, ad_);
    aggregate_kernel<<<NN, 256, 0, stream>>>(bufA, csr_src, offsets, as_, ad_, b2, bufB);

    // ---- pool + BN + linear ----
    pool_kernel<<<GG * PSLICE, 256, 0, stream>>>(bufB, start, pool);
    final_kernel<<<GG, 256, 0, stream>>>(pool, cnt, bn_g, bn_b, bn_m, bn_v, Wl, bl, out);
}